// Round 11
// baseline (102.978 us; speedup 1.0000x reference)
//
#include <hip/hip_runtime.h>
#include <math.h>

// SACConv: B=8, C1=C2=16, K=3, S=1, H=W=64, HDIM=16, N=C1*K*K=144, L=4096
//
// out[b,l,c] = Qb[l,c] + sum_j h[l,j]*Qw[l,c*16+j]
//   Q[32768 x 272] = P[32768 x 144] @ Wcat[144 x 272]   (bf16 MFMA, K padded 160)
//   cols 0..255: (c,j) -> c*16+j from fc2_w ; cols 256..271: bias col c
//
// R11 = R9 structure + FUSED prep (single dispatch):
//  - blocks 0..84 build one Bfrag tile each at kernel start (coalesced float4
//    loads -> LDS transpose Td[32][17] aliased into SA -> wave0 frag store),
//    then device-scope release a per-tile flag in d_ws (0xAA poison = "not
//    ready", no zero-init needed).
//  - all blocks spin on flags (relaxed agent loads, t<85) just before barrier 1
//    (after x-staging + stats -> spin is ~free), then __threadfence() acquire.
//  - B prefetches moved after barrier 1 (covered by af ds_reads).
//  - Hl transposed [16][68] (R10b: epilogue reads lane-stride-1, conflict-free).
//  - Q dump = R9 scalar b16 (R10a's shfl pack REGRESSED: __shfl = ds_bpermute
//    on the LDS pipe -- net more LDS issue, not less).
// Everything else verbatim R9 (x via LDS w/ zero halo, shuffle stats,
// full B dedup, 3-buffer B prefetch rotation).

typedef __attribute__((ext_vector_type(8))) short short8;
typedef __attribute__((ext_vector_type(4))) float float4v;

#define NPq 144
#define QSTR 280        // Qs row stride (hw)
#define MAGICF 0x13572468u

__device__ __forceinline__ unsigned short f2bf(float f) {
    unsigned int u = __builtin_bit_cast(unsigned int, f);
    u += 0x7fffu + ((u >> 16) & 1u);
    return (unsigned short)(u >> 16);
}
__device__ __forceinline__ float bf2f(unsigned short h) {
    unsigned int u = ((unsigned int)h) << 16;
    return __builtin_bit_cast(float, u);
}

__global__ __launch_bounds__(256, 2) void sacconv_kernel(
    const float* __restrict__ x,
    const float* __restrict__ fc1_w,
    const float* __restrict__ fc1_b,
    const float* __restrict__ fc2_w,
    const float* __restrict__ fc2_b,
    unsigned short* Bfrag,            // d_ws[0..87040): 85 tiles x 64 lanes x 8 bf16
    unsigned int*   flags,            // d_ws[87296..): 85 release flags
    float* __restrict__ out)
{
    __shared__ unsigned short SA[4 * 5 * 64 * 8];                          // 20480 B
    __shared__ __attribute__((aligned(16))) unsigned short Qs[64 * QSTR];  // 35840 B
    __shared__ float Hl[16 * 68];                                          //  4352 B

    const int t   = threadIdx.x;
    const int blk = blockIdx.x;     // 512
    const int b   = blk >> 6;
    const int y   = blk & 63;

    const int lane = t & 63;
    const int w    = __builtin_amdgcn_readfirstlane(t >> 6);   // wave id
    const int m    = lane & 15;
    const int q    = lane >> 4;
    const int loc  = w * 16 + m;    // this lane's location

    // ================= fused prep: blocks 0..84 build Bfrag tile blk =================
    // Bfrag[(tt*5+ss)*64 + lane] = 8 bf16 of B[k = ss*32+(lane>>4)*8+j][n = lane&15]
    // tt<16: B[k][n] = fc2_w[(tt*144+k)*16+n]; tt==16: fc2_b[n*144+k]; k>=144 -> 0
    if (blk < 85) {
        const int tt = blk / 5, ss = blk % 5;
        if (tt < 16) {
            float* Td = (float*)SA;             // 32 k-rows x 16 n, stride 17 (2176 B)
            if (t < 128) {                      // coalesced: 8 KB contiguous
                const int rr = t >> 2, cs = t & 3;
                const int k  = ss * 32 + rr;
                float4 d = make_float4(0.f, 0.f, 0.f, 0.f);
                if (k < NPq) d = *(const float4*)&fc2_w[(tt * NPq + k) * 16 + cs * 4];
                Td[rr * 17 + cs * 4 + 0] = d.x;
                Td[rr * 17 + cs * 4 + 1] = d.y;
                Td[rr * 17 + cs * 4 + 2] = d.z;
                Td[rr * 17 + cs * 4 + 3] = d.w;
            }
            __syncthreads();
            if (t < 64) {
                const int n = t & 15, qq = t >> 4;
                short8 v;
#pragma unroll
                for (int j = 0; j < 8; ++j)
                    v[j] = (short)f2bf(Td[(qq * 8 + j) * 17 + n]);
                *(short8*)(Bfrag + (size_t)(blk * 64 + t) * 8) = v;
            }
        } else {                                // bias tile (blk 80..84)
            if (t < 64) {
                const int n = t & 15, qq = t >> 4;
                const int kb = ss * 32 + qq * 8;
                float4 d0 = make_float4(0.f, 0.f, 0.f, 0.f), d1 = d0;
                if (kb < NPq) {
                    d0 = *(const float4*)&fc2_b[n * NPq + kb];
                    d1 = *(const float4*)&fc2_b[n * NPq + kb + 4];
                }
                short8 v;
                v[0] = (short)f2bf(d0.x); v[1] = (short)f2bf(d0.y);
                v[2] = (short)f2bf(d0.z); v[3] = (short)f2bf(d0.w);
                v[4] = (short)f2bf(d1.x); v[5] = (short)f2bf(d1.y);
                v[6] = (short)f2bf(d1.z); v[7] = (short)f2bf(d1.w);
                *(short8*)(Bfrag + (size_t)(blk * 64 + t) * 8) = v;
            }
        }
        __syncthreads();                        // drains vmcnt(0): Bfrag stores done
        if (t == 0) {
            __threadfence();                    // device release (L2 writeback)
            __hip_atomic_store(&flags[blk], MAGICF, __ATOMIC_RELEASE,
                               __HIP_MEMORY_SCOPE_AGENT);
        }
    }

    // Xs aliases Qs (dead until Q dump). Guard quad at XsG[0..3] catches the
    // ch=0,dy=0,xp=-1 underflow.
    float* XsG = (float*)Qs;
    float* Xs  = XsG + 4;           // Xs[ch*204 + dy*68 + col], col 0..67

    // ---------- stage x rows {y-1,y,y+1} x 16ch into Xs, halo zeroed ----------
    {
        const float4 z4 = make_float4(0.f, 0.f, 0.f, 0.f);
        if (t < 48) *(float4*)&Xs[t * 68 + 64] = z4;    // halo cols 64..67
        if (t == 48) *(float4*)&XsG[0] = z4;            // guard quad
        const int ybad = (y == 0) ? 0 : ((y == 63) ? 2 : -1);
        if (ybad >= 0) {
#pragma unroll
            for (int u = 0; u < 2; ++u) {
                const int idx = t + 256 * u;            // < 272 = 16ch * 17quads
                if (idx < 272) {
                    const int ch = idx / 17, sg = idx % 17;
                    *(float4*)&Xs[ch * 204 + ybad * 68 + sg * 4] = z4;
                }
            }
        }
#pragma unroll
        for (int u = 0; u < 3; ++u) {
            const int idx = t + 256 * u;                // < 768 = 48 rows x 16 segs
            const int r  = idx >> 4, sg = idx & 15;
            const int ch = r / 3;
            const int dy = r - ch * 3;
            const int yy = y + dy - 1;
            if (yy >= 0 && yy < 64) {
                const float4 d = *(const float4*)&x[(((b * 16 + ch) * 64 + yy) << 6) + sg * 4];
                *(float4*)&Xs[r * 68 + sg * 4] = d;
            }
        }
    }
    __syncthreads();   // barrier A: Xs complete (also closes prep's Td use of SA)

    // ---------- gather: 36 unconditional ds_read_b32 (2-way banks = free) ----------
    float v[36];
    float sum = 0.f, mx = -1e30f;
    {
        const float* basep = &Xs[q * 816 + loc - 1];
#pragma unroll
        for (int i = 0; i < 36; ++i) {
            const int g  = i / 9;               // compile-time
            const int r9 = i % 9;
            const int ii = r9 / 3, jj = r9 % 3; // compile-time
            const float val = basep[g * 204 + ii * 68 + jj];
            v[i] = val;
            sum += val;
            mx  = fmaxf(mx, val);
        }
    }

    // ---------- stage A-frags (lane's o-range [36q,36q+36) -> 4xb128+1xb64) ----------
    {
        unsigned int pk[18];
#pragma unroll
        for (int p = 0; p < 18; ++p)
            pk[p] = (unsigned int)f2bf(v[2 * p]) | ((unsigned int)f2bf(v[2 * p + 1]) << 16);
        const int g0 = (36 * q) >> 3;
        auto hwa = [&](int g) { return ((w * 5 + (g >> 2)) * 64 + (g & 3) * 16 + m) * 8; };
        if ((q & 1) == 0) {
#pragma unroll
            for (int u = 0; u < 4; ++u)
                *(uint4*)&SA[hwa(g0 + u)] = make_uint4(pk[4*u], pk[4*u+1], pk[4*u+2], pk[4*u+3]);
            *(uint2*)&SA[hwa(g0 + 4)] = make_uint2(pk[16], pk[17]);
        } else {
            *(uint2*)&SA[hwa(g0) + 4] = make_uint2(pk[0], pk[1]);
#pragma unroll
            for (int u = 0; u < 4; ++u)
                *(uint4*)&SA[hwa(g0 + 1 + u)] = make_uint4(pk[4*u+2], pk[4*u+3], pk[4*u+4], pk[4*u+5]);
        }
        if (lane < 32)
            *(uint4*)&SA[((w * 5 + 4) * 64 + 32 + lane) * 8] = make_uint4(0u, 0u, 0u, 0u);
    }

    // ---------- shuffle stats (4 lanes m, m+16, m+32, m+48 share loc) ----------
    sum += __shfl_xor(sum, 16, 64);
    sum += __shfl_xor(sum, 32, 64);
    mx = fmaxf(mx, __shfl_xor(mx, 16, 64));
    mx = fmaxf(mx, __shfl_xor(mx, 32, 64));
    const float mu = sum * (1.f / 144.f);

    float m2 = 0.f, m3 = 0.f, m4 = 0.f, se = 0.f, sev = 0.f;
#pragma unroll
    for (int i = 0; i < 36; ++i) {
        const float d  = v[i] - mu;
        const float d2 = d * d;
        m2 += d2; m3 += d2 * d; m4 += d2 * d2;
        const float e = __expf(v[i] - mx);
        se += e; sev += e * v[i];
    }
    m2 += __shfl_xor(m2, 16, 64);  m2 += __shfl_xor(m2, 32, 64);
    m3 += __shfl_xor(m3, 16, 64);  m3 += __shfl_xor(m3, 32, 64);
    m4 += __shfl_xor(m4, 16, 64);  m4 += __shfl_xor(m4, 32, 64);
    se += __shfl_xor(se, 16, 64);  se += __shfl_xor(se, 32, 64);
    sev += __shfl_xor(sev, 16, 64); sev += __shfl_xor(sev, 32, 64);

    const float var   = m2 * (1.f / 143.f);           // ddof=1
    const float sigma = sqrtf(var) + 1e-6f;
    const float is    = 1.f / sigma;
    const float is2   = is * is;
    const float skew  = (m3 * (1.f / 144.f)) * is2 * is;
    const float kurt  = (m4 * (1.f / 144.f)) * is2 * is2 - 3.f;
    const float ent   = __logf(se) + mx - sev / se;   // validated R5-R10

    // ---------- h: lane (m,q) computes j = q*4..q*4+3; Hl transposed [j][loc] ----------
    {
#pragma unroll
        for (int j0 = 0; j0 < 4; ++j0) {
            const int j = q * 4 + j0;
            const float* wr = fc1_w + j * 5;
            const float hv = mu * wr[0] + sigma * wr[1] + skew * wr[2]
                           + kurt * wr[3] + ent * wr[4] + fc1_b[j];
            Hl[j * 68 + loc] = fmaxf(hv, 0.f);
        }
    }

    // ---------- wait for all Bfrag tiles (usually instant by now) ----------
    if (t < 85) {
        while (__hip_atomic_load(&flags[t], __ATOMIC_RELAXED,
                                 __HIP_MEMORY_SCOPE_AGENT) != MAGICF)
            __builtin_amdgcn_s_sleep(1);
    }
    __threadfence();   // acquire: invalidate stale L1/L2 before Bfrag reads
    __syncthreads();   // barrier 1: A-frags + Hl visible; Bfrag ready; Xs dead

    // ---------- MFMA: wave w -> n-tiles {w, w+4, w+8, w+12} (+16 if w==3), all 4 m-tiles ----------
    const short8* Bf = (const short8*)Bfrag;
    short8 bb0[5], bb1[5], bb2[5];
#pragma unroll
    for (int s = 0; s < 5; ++s) bb0[s] = Bf[(w * 5 + s) * 64 + lane];
#pragma unroll
    for (int s = 0; s < 5; ++s) bb1[s] = Bf[((w + 4) * 5 + s) * 64 + lane];

    short8 af[4][5];   // ds_reads issue while B loads are in flight
#pragma unroll
    for (int mm = 0; mm < 4; ++mm)
#pragma unroll
        for (int s = 0; s < 5; ++s)
            af[mm][s] = *(const short8*)&SA[((mm * 5 + s) * 64 + lane) * 8];

    float4v acc[4][4];
#pragma unroll
    for (int u = 0; u < 4; ++u)
#pragma unroll
        for (int mm = 0; mm < 4; ++mm) acc[u][mm] = (float4v){0.f, 0.f, 0.f, 0.f};
    float4v acc4[4];
#pragma unroll
    for (int mm = 0; mm < 4; ++mm) acc4[mm] = (float4v){0.f, 0.f, 0.f, 0.f};

    // u=0: consume bb0 (tile w); prefetch tile w+8
#pragma unroll
    for (int s = 0; s < 5; ++s) bb2[s] = Bf[((w + 8) * 5 + s) * 64 + lane];
#pragma unroll
    for (int mm = 0; mm < 4; ++mm)
#pragma unroll
        for (int s = 0; s < 5; ++s)
            acc[0][mm] = __builtin_amdgcn_mfma_f32_16x16x32_bf16(af[mm][s], bb0[s], acc[0][mm], 0, 0, 0);

    // u=1: consume bb1 (tile w+4); prefetch tile w+12 into bb0
#pragma unroll
    for (int s = 0; s < 5; ++s) bb0[s] = Bf[((w + 12) * 5 + s) * 64 + lane];
#pragma unroll
    for (int mm = 0; mm < 4; ++mm)
#pragma unroll
        for (int s = 0; s < 5; ++s)
            acc[1][mm] = __builtin_amdgcn_mfma_f32_16x16x32_bf16(af[mm][s], bb1[s], acc[1][mm], 0, 0, 0);

    // u=2: consume bb2 (tile w+8); w==3 prefetches bias tile 16 into bb1
    if (w == 3) {
#pragma unroll
        for (int s = 0; s < 5; ++s) bb1[s] = Bf[(16 * 5 + s) * 64 + lane];
    }
#pragma unroll
    for (int mm = 0; mm < 4; ++mm)
#pragma unroll
        for (int s = 0; s < 5; ++s)
            acc[2][mm] = __builtin_amdgcn_mfma_f32_16x16x32_bf16(af[mm][s], bb2[s], acc[2][mm], 0, 0, 0);

    // u=3: consume bb0 (tile w+12)
#pragma unroll
    for (int mm = 0; mm < 4; ++mm)
#pragma unroll
        for (int s = 0; s < 5; ++s)
            acc[3][mm] = __builtin_amdgcn_mfma_f32_16x16x32_bf16(af[mm][s], bb0[s], acc[3][mm], 0, 0, 0);

    // u=4 (w==3 only): bias tile
    if (w == 3) {
#pragma unroll
        for (int mm = 0; mm < 4; ++mm)
#pragma unroll
            for (int s = 0; s < 5; ++s)
                acc4[mm] = __builtin_amdgcn_mfma_f32_16x16x32_bf16(af[mm][s], bb1[s], acc4[mm], 0, 0, 0);
    }

    // ---------- dump Q to Qs (C layout: col=lane&15, row=(lane>>4)*4+r) ----------
    {
        const int nn = lane & 15, qq = lane >> 4;
#pragma unroll
        for (int u = 0; u < 4; ++u) {
            const int col = (w + 4 * u) * 16 + nn;
#pragma unroll
            for (int mm = 0; mm < 4; ++mm) {
                const int rowb = mm * 16 + qq * 4;
#pragma unroll
                for (int r = 0; r < 4; ++r)
                    Qs[(rowb + r) * QSTR + col] = f2bf(acc[u][mm][r]);
            }
        }
        if (w == 3) {
#pragma unroll
            for (int mm = 0; mm < 4; ++mm) {
                const int rowb = mm * 16 + qq * 4;
#pragma unroll
                for (int r = 0; r < 4; ++r)
                    Qs[(rowb + r) * QSTR + 256 + nn] = f2bf(acc4[mm][r]);
            }
        }
    }
    __syncthreads();   // barrier 2: Q complete

    // ---------- fold h, write out (lane = loc' 0..63, c-group w*4..w*4+3) ----------
    {
        float hv[16];
#pragma unroll
        for (int j = 0; j < 16; ++j) hv[j] = Hl[j * 68 + lane];   // stride-1: free
        const int cg = w * 4;
#pragma unroll
        for (int cc = 0; cc < 4; ++cc) {
            const int c = cg + cc;
            const unsigned short* qr = &Qs[lane * QSTR + c * 16];
            short8 q0 = *(const short8*)qr;
            short8 q1 = *(const short8*)(qr + 8);
            float res = bf2f(Qs[lane * QSTR + 256 + c]);
#pragma unroll
            for (int j = 0; j < 8; ++j) res += hv[j]     * bf2f((unsigned short)q0[j]);
#pragma unroll
            for (int j = 0; j < 8; ++j) res += hv[8 + j] * bf2f((unsigned short)q1[j]);
            out[(b * 16 + c) * 4096 + y * 64 + lane] = res;
        }
    }
}

extern "C" void kernel_launch(void* const* d_in, const int* in_sizes, int n_in,
                              void* d_out, int out_size, void* d_ws, size_t ws_size,
                              hipStream_t stream) {
    const float* x     = (const float*)d_in[0];
    const float* fc1_w = (const float*)d_in[1];
    const float* fc1_b = (const float*)d_in[2];
    const float* fc2_w = (const float*)d_in[3];
    const float* fc2_b = (const float*)d_in[4];
    float* out = (float*)d_out;
    unsigned short* Bfrag = (unsigned short*)d_ws;                    // 87040 B
    unsigned int*   flags = (unsigned int*)((char*)d_ws + 87296);     // 85 flags

    sacconv_kernel<<<512, 256, 0, stream>>>(x, fc1_w, fc1_b, fc2_w, fc2_b,
                                            Bfrag, flags, out);
}

// Round 12
// 71.542 us; speedup vs baseline: 1.4394x; 1.4394x over previous
//
#include <hip/hip_runtime.h>
#include <math.h>

// SACConv: B=8, C1=C2=16, K=3, S=1, H=W=64, HDIM=16, N=C1*K*K=144, L=4096
//
// out[b,l,c] = Qb[l,c] + sum_j h[l,j]*Qw[l,c*16+j]
//   Q[32768 x 272] = P[32768 x 144] @ Wcat[144 x 272]   (bf16 MFMA, K padded 160)
//   cols 0..255: (c,j) -> c*16+j from fc2_w ; cols 256..271: bias col c
//
// R12 = R9 (best measured: 70.7) + R10's two untested-positive fixes only:
//  (b) Hl transposed [16][68]: epilogue h reads lane-stride-1, conflict-free.
//  (c) prep: coalesced float4 fc2_w reads -> LDS transpose -> frag order.
// R10a (shfl Q-dump) NOT included: __shfl = ds_bpermute on the LDS pipe,
// measured -2.4us. R11 (fused prep via flags+fence) NOT included: the
// acquire-fence/spin path cost ~25us (sacconv 45us, MfmaUtil 2%).
// Two dispatches; R9 main path verbatim otherwise.

typedef __attribute__((ext_vector_type(8))) short short8;
typedef __attribute__((ext_vector_type(4))) float float4v;

#define NPq 144
#define QSTR 280   // Qs row stride (hw): 560 B, 16B-aligned rows

__device__ __forceinline__ unsigned short f2bf(float f) {
    unsigned int u = __builtin_bit_cast(unsigned int, f);
    u += 0x7fffu + ((u >> 16) & 1u);
    return (unsigned short)(u >> 16);
}
__device__ __forceinline__ float bf2f(unsigned short h) {
    unsigned int u = ((unsigned int)h) << 16;
    return __builtin_bit_cast(float, u);
}

// ---------- prep: B fragments, coalesced via LDS transpose (R10c) ----------
// Bfrag[(t*5+s)*64 + lane] = 8 bf16 of B[k = s*32+(lane>>4)*8+j][n = lane&15]
// t<16: B[k][n] = fc2_w[(t*144+k)*16+n]; t==16: fc2_b[n*144+k]; k>=144 -> 0
__global__ void prep_bfrag(const float* __restrict__ fc2_w,
                           const float* __restrict__ fc2_b,
                           unsigned short* __restrict__ Bfrag) {
    __shared__ float Td[32 * 21];          // 32 k-rows x 16 n-cols, stride 21
    const int blk  = blockIdx.x;           // 85 = 17*5
    const int t    = blk / 5, s = blk % 5;
    const int lane = threadIdx.x;          // 64 = 1 wave
    const int n    = lane & 15, q = lane >> 4;
    short8 v;

    if (t < 16) {
        // coalesced: 128 float4 = 32 rows x 4 segs; lane does f = 2*lane, 2*lane+1
#pragma unroll
        for (int u = 0; u < 2; ++u) {
            const int f  = lane * 2 + u;
            const int rr = f >> 2, cs = f & 3;       // k-row rr, col-seg cs
            const int k  = s * 32 + rr;
            float4 d = make_float4(0.f, 0.f, 0.f, 0.f);
            if (k < NPq)
                d = *(const float4*)&fc2_w[(t * NPq + k) * 16 + cs * 4];
            Td[rr * 21 + cs * 4 + 0] = d.x;
            Td[rr * 21 + cs * 4 + 1] = d.y;
            Td[rr * 21 + cs * 4 + 2] = d.z;
            Td[rr * 21 + cs * 4 + 3] = d.w;
        }
        __syncthreads();                    // 1 wave: just drains lgkm
#pragma unroll
        for (int j = 0; j < 8; ++j)
            v[j] = (short)f2bf(Td[(q * 8 + j) * 21 + n]);
    } else {
        // bias tile: lane's 8 k's contiguous in fc2_b -> 2 aligned float4
        float4 d0 = make_float4(0.f, 0.f, 0.f, 0.f), d1 = d0;
        if (s * 32 + q * 8 < NPq) {
            d0 = *(const float4*)&fc2_b[n * NPq + s * 32 + q * 8];
            d1 = *(const float4*)&fc2_b[n * NPq + s * 32 + q * 8 + 4];
        }
        v[0] = (short)f2bf(d0.x); v[1] = (short)f2bf(d0.y);
        v[2] = (short)f2bf(d0.z); v[3] = (short)f2bf(d0.w);
        v[4] = (short)f2bf(d1.x); v[5] = (short)f2bf(d1.y);
        v[6] = (short)f2bf(d1.z); v[7] = (short)f2bf(d1.w);
    }
    *(short8*)(Bfrag + (size_t)(blk * 64 + lane) * 8) = v;
}

// ---------- main (R9 verbatim except Hl transposed) ----------
__global__ __launch_bounds__(256, 2) void sacconv_kernel(
    const float* __restrict__ x,
    const float* __restrict__ fc1_w,
    const float* __restrict__ fc1_b,
    const unsigned short* __restrict__ Bfrag,
    float* __restrict__ out)
{
    __shared__ unsigned short SA[4 * 5 * 64 * 8];                          // 20480 B
    __shared__ __attribute__((aligned(16))) unsigned short Qs[64 * QSTR];  // 35840 B
    __shared__ float Hl[16 * 68];                                          //  4352 B

    const int t   = threadIdx.x;
    const int blk = blockIdx.x;     // 512
    const int b   = blk >> 6;
    const int y   = blk & 63;

    const int lane = t & 63;
    const int w    = __builtin_amdgcn_readfirstlane(t >> 6);   // wave id
    const int m    = lane & 15;
    const int q    = lane >> 4;
    const int loc  = w * 16 + m;    // this lane's location

    // Xs aliases Qs (dead until Q dump). Guard quad at XsG[0..3] catches the
    // ch=0,dy=0,xp=-1 underflow.
    float* XsG = (float*)Qs;
    float* Xs  = XsG + 4;           // Xs[ch*204 + dy*68 + col], col 0..67

    // ---------- earliest possible B issue: tile w (hidden behind staging/stats) ----------
    const short8* Bf = (const short8*)Bfrag;
    short8 bb0[5], bb1[5], bb2[5];
#pragma unroll
    for (int s = 0; s < 5; ++s) bb0[s] = Bf[(w * 5 + s) * 64 + lane];

    // ---------- stage x rows {y-1,y,y+1} x 16ch into Xs, halo zeroed ----------
    {
        const float4 z4 = make_float4(0.f, 0.f, 0.f, 0.f);
        if (t < 48) *(float4*)&Xs[t * 68 + 64] = z4;    // halo cols 64..67
        if (t == 48) *(float4*)&XsG[0] = z4;            // guard quad
        const int ybad = (y == 0) ? 0 : ((y == 63) ? 2 : -1);
        if (ybad >= 0) {
#pragma unroll
            for (int u = 0; u < 2; ++u) {
                const int idx = t + 256 * u;            // < 272 = 16ch * 17quads
                if (idx < 272) {
                    const int ch = idx / 17, sg = idx % 17;
                    *(float4*)&Xs[ch * 204 + ybad * 68 + sg * 4] = z4;
                }
            }
        }
#pragma unroll
        for (int u = 0; u < 3; ++u) {
            const int idx = t + 256 * u;                // < 768 = 48 rows x 16 segs
            const int r  = idx >> 4, sg = idx & 15;
            const int ch = r / 3;
            const int dy = r - ch * 3;
            const int yy = y + dy - 1;
            if (yy >= 0 && yy < 64) {
                const float4 d = *(const float4*)&x[(((b * 16 + ch) * 64 + yy) << 6) + sg * 4];
                *(float4*)&Xs[r * 68 + sg * 4] = d;
            }
        }
    }
    __syncthreads();   // barrier A: Xs complete

    // ---------- gather: 36 unconditional ds_read_b32 (2-way banks = free) ----------
    float v[36];
    float sum = 0.f, mx = -1e30f;
    {
        const float* basep = &Xs[q * 816 + loc - 1];
#pragma unroll
        for (int i = 0; i < 36; ++i) {
            const int g  = i / 9;               // compile-time
            const int r9 = i % 9;
            const int ii = r9 / 3, jj = r9 % 3; // compile-time
            const float val = basep[g * 204 + ii * 68 + jj];
            v[i] = val;
            sum += val;
            mx  = fmaxf(mx, val);
        }
    }

    // ---------- stage A-frags (lane's o-range [36q,36q+36) -> 4xb128+1xb64) ----------
    {
        unsigned int pk[18];
#pragma unroll
        for (int p = 0; p < 18; ++p)
            pk[p] = (unsigned int)f2bf(v[2 * p]) | ((unsigned int)f2bf(v[2 * p + 1]) << 16);
        const int g0 = (36 * q) >> 3;
        auto hwa = [&](int g) { return ((w * 5 + (g >> 2)) * 64 + (g & 3) * 16 + m) * 8; };
        if ((q & 1) == 0) {
#pragma unroll
            for (int u = 0; u < 4; ++u)
                *(uint4*)&SA[hwa(g0 + u)] = make_uint4(pk[4*u], pk[4*u+1], pk[4*u+2], pk[4*u+3]);
            *(uint2*)&SA[hwa(g0 + 4)] = make_uint2(pk[16], pk[17]);
        } else {
            *(uint2*)&SA[hwa(g0) + 4] = make_uint2(pk[0], pk[1]);
#pragma unroll
            for (int u = 0; u < 4; ++u)
                *(uint4*)&SA[hwa(g0 + 1 + u)] = make_uint4(pk[4*u+2], pk[4*u+3], pk[4*u+4], pk[4*u+5]);
        }
        if (lane < 32)
            *(uint4*)&SA[((w * 5 + 4) * 64 + 32 + lane) * 8] = make_uint4(0u, 0u, 0u, 0u);
    }

    // ---------- shuffle stats (4 lanes m, m+16, m+32, m+48 share loc) ----------
    sum += __shfl_xor(sum, 16, 64);
    sum += __shfl_xor(sum, 32, 64);
    mx = fmaxf(mx, __shfl_xor(mx, 16, 64));
    mx = fmaxf(mx, __shfl_xor(mx, 32, 64));
    const float mu = sum * (1.f / 144.f);

    float m2 = 0.f, m3 = 0.f, m4 = 0.f, se = 0.f, sev = 0.f;
#pragma unroll
    for (int i = 0; i < 36; ++i) {
        const float d  = v[i] - mu;
        const float d2 = d * d;
        m2 += d2; m3 += d2 * d; m4 += d2 * d2;
        const float e = __expf(v[i] - mx);
        se += e; sev += e * v[i];
    }
    m2 += __shfl_xor(m2, 16, 64);  m2 += __shfl_xor(m2, 32, 64);
    m3 += __shfl_xor(m3, 16, 64);  m3 += __shfl_xor(m3, 32, 64);
    m4 += __shfl_xor(m4, 16, 64);  m4 += __shfl_xor(m4, 32, 64);
    se += __shfl_xor(se, 16, 64);  se += __shfl_xor(se, 32, 64);
    sev += __shfl_xor(sev, 16, 64); sev += __shfl_xor(sev, 32, 64);

    const float var   = m2 * (1.f / 143.f);           // ddof=1
    const float sigma = sqrtf(var) + 1e-6f;
    const float is    = 1.f / sigma;
    const float is2   = is * is;
    const float skew  = (m3 * (1.f / 144.f)) * is2 * is;
    const float kurt  = (m4 * (1.f / 144.f)) * is2 * is2 - 3.f;
    const float ent   = __logf(se) + mx - sev / se;   // validated R5-R11

    // ---------- h: lane (m,q) computes j = q*4..q*4+3; Hl transposed [j][loc] ----------
    {
#pragma unroll
        for (int j0 = 0; j0 < 4; ++j0) {
            const int j = q * 4 + j0;
            const float* wr = fc1_w + j * 5;
            const float hv = mu * wr[0] + sigma * wr[1] + skew * wr[2]
                           + kurt * wr[3] + ent * wr[4] + fc1_b[j];
            Hl[j * 68 + loc] = fmaxf(hv, 0.f);
        }
    }

    // ---------- prefetch B tile w+4 before the barrier ----------
#pragma unroll
    for (int s = 0; s < 5; ++s) bb1[s] = Bf[((w + 4) * 5 + s) * 64 + lane];

    __syncthreads();   // barrier 1: A-frags + Hl visible (Xs now dead)

    // ---------- MFMA: wave w -> n-tiles {w, w+4, w+8, w+12} (+16 if w==3), all 4 m-tiles ----------
    short8 af[4][5];
#pragma unroll
    for (int mm = 0; mm < 4; ++mm)
#pragma unroll
        for (int s = 0; s < 5; ++s)
            af[mm][s] = *(const short8*)&SA[((mm * 5 + s) * 64 + lane) * 8];

    float4v acc[4][4];
#pragma unroll
    for (int u = 0; u < 4; ++u)
#pragma unroll
        for (int mm = 0; mm < 4; ++mm) acc[u][mm] = (float4v){0.f, 0.f, 0.f, 0.f};
    float4v acc4[4];
#pragma unroll
    for (int mm = 0; mm < 4; ++mm) acc4[mm] = (float4v){0.f, 0.f, 0.f, 0.f};

    // u=0: consume bb0 (tile w); prefetch tile w+8
#pragma unroll
    for (int s = 0; s < 5; ++s) bb2[s] = Bf[((w + 8) * 5 + s) * 64 + lane];
#pragma unroll
    for (int mm = 0; mm < 4; ++mm)
#pragma unroll
        for (int s = 0; s < 5; ++s)
            acc[0][mm] = __builtin_amdgcn_mfma_f32_16x16x32_bf16(af[mm][s], bb0[s], acc[0][mm], 0, 0, 0);

    // u=1: consume bb1 (tile w+4); prefetch tile w+12 into bb0
#pragma unroll
    for (int s = 0; s < 5; ++s) bb0[s] = Bf[((w + 12) * 5 + s) * 64 + lane];
#pragma unroll
    for (int mm = 0; mm < 4; ++mm)
#pragma unroll
        for (int s = 0; s < 5; ++s)
            acc[1][mm] = __builtin_amdgcn_mfma_f32_16x16x32_bf16(af[mm][s], bb1[s], acc[1][mm], 0, 0, 0);

    // u=2: consume bb2 (tile w+8); w==3 prefetches bias tile 16 into bb1
    if (w == 3) {
#pragma unroll
        for (int s = 0; s < 5; ++s) bb1[s] = Bf[(16 * 5 + s) * 64 + lane];
    }
#pragma unroll
    for (int mm = 0; mm < 4; ++mm)
#pragma unroll
        for (int s = 0; s < 5; ++s)
            acc[2][mm] = __builtin_amdgcn_mfma_f32_16x16x32_bf16(af[mm][s], bb2[s], acc[2][mm], 0, 0, 0);

    // u=3: consume bb0 (tile w+12)
#pragma unroll
    for (int mm = 0; mm < 4; ++mm)
#pragma unroll
        for (int s = 0; s < 5; ++s)
            acc[3][mm] = __builtin_amdgcn_mfma_f32_16x16x32_bf16(af[mm][s], bb0[s], acc[3][mm], 0, 0, 0);

    // u=4 (w==3 only): bias tile
    if (w == 3) {
#pragma unroll
        for (int mm = 0; mm < 4; ++mm)
#pragma unroll
            for (int s = 0; s < 5; ++s)
                acc4[mm] = __builtin_amdgcn_mfma_f32_16x16x32_bf16(af[mm][s], bb1[s], acc4[mm], 0, 0, 0);
    }

    // ---------- dump Q to Qs (C layout: col=lane&15, row=(lane>>4)*4+r) ----------
    {
        const int nn = lane & 15, qq = lane >> 4;
#pragma unroll
        for (int u = 0; u < 4; ++u) {
            const int col = (w + 4 * u) * 16 + nn;
#pragma unroll
            for (int mm = 0; mm < 4; ++mm) {
                const int rowb = mm * 16 + qq * 4;
#pragma unroll
                for (int r = 0; r < 4; ++r)
                    Qs[(rowb + r) * QSTR + col] = f2bf(acc[u][mm][r]);
            }
        }
        if (w == 3) {
#pragma unroll
            for (int mm = 0; mm < 4; ++mm) {
                const int rowb = mm * 16 + qq * 4;
#pragma unroll
                for (int r = 0; r < 4; ++r)
                    Qs[(rowb + r) * QSTR + 256 + nn] = f2bf(acc4[mm][r]);
            }
        }
    }
    __syncthreads();   // barrier 2: Q complete

    // ---------- fold h, write out (lane = loc' 0..63, c-group w*4..w*4+3) ----------
    {
        float hv[16];
#pragma unroll
        for (int j = 0; j < 16; ++j) hv[j] = Hl[j * 68 + lane];   // stride-1: free
        const int cg = w * 4;
#pragma unroll
        for (int cc = 0; cc < 4; ++cc) {
            const int c = cg + cc;
            const unsigned short* qr = &Qs[lane * QSTR + c * 16];
            short8 q0 = *(const short8*)qr;
            short8 q1 = *(const short8*)(qr + 8);
            float res = bf2f(Qs[lane * QSTR + 256 + c]);
#pragma unroll
            for (int j = 0; j < 8; ++j) res += hv[j]     * bf2f((unsigned short)q0[j]);
#pragma unroll
            for (int j = 0; j < 8; ++j) res += hv[8 + j] * bf2f((unsigned short)q1[j]);
            out[(b * 16 + c) * 4096 + y * 64 + lane] = res;
        }
    }
}

extern "C" void kernel_launch(void* const* d_in, const int* in_sizes, int n_in,
                              void* d_out, int out_size, void* d_ws, size_t ws_size,
                              hipStream_t stream) {
    const float* x     = (const float*)d_in[0];
    const float* fc1_w = (const float*)d_in[1];
    const float* fc1_b = (const float*)d_in[2];
    const float* fc2_w = (const float*)d_in[3];
    const float* fc2_b = (const float*)d_in[4];
    float* out = (float*)d_out;
    unsigned short* Bfrag = (unsigned short*)d_ws;   // 85*64*8*2 = 87040 B

    prep_bfrag<<<85, 64, 0, stream>>>(fc2_w, fc2_b, Bfrag);
    sacconv_kernel<<<512, 256, 0, stream>>>(x, fc1_w, fc1_b, Bfrag, out);
}